// Round 11
// baseline (327.940 us; speedup 1.0000x reference)
//
#include <hip/hip_runtime.h>
#include <hip/hip_fp16.h>
#include <math.h>

#define MROWS   65536
#define NCODES  1024
#define KD      256
#define MARGIN  0.25f

typedef unsigned short u16;
typedef __attribute__((ext_vector_type(8))) _Float16 hfrag;  // 8 fp16 = 4 VGPR
typedef __attribute__((ext_vector_type(4))) float f32x4;

// d_out bytes: [0,32M) Ah fp16 scratch | [32M,36M) refine partials | all of [0,64M)
//   overwritten by vq_gather at the end | idx (floats) at [64M, +256K).
// d_ws:  [0,512K) Eh | [512K,+4K) esq | [1M,+2M) tw | [3.5M] cnt | +256B list
#define IOFF ((size_t)MROWS * KD)

// ---- asm-rounded fp32 add (contraction/reassociation-proof) ---------------
__device__ __forceinline__ float addrn(float a, float b) {
    float d; asm("v_add_f32 %0, %1, %2" : "=v"(d) : "v"(a), "v"(b)); return d;
}

// ---- exact VF8-IC4 sum of squares of a 256-row (R8-verified bits) ---------
__device__ __forceinline__ float sumsq_vf8ic4(const float* __restrict__ xr) {
    float a[4][8];
#pragma unroll
    for (int i = 0; i < 4; ++i)
#pragma unroll
        for (int l = 0; l < 8; ++l) a[i][l] = 0.f;
#pragma unroll
    for (int m = 0; m < 8; ++m)
#pragma unroll
        for (int i = 0; i < 4; ++i)
#pragma unroll
            for (int l = 0; l < 8; ++l) {
                float v = xr[m * 32 + i * 8 + l];
                a[i][l] = fmaf(v, v, a[i][l]);
            }
    float cc[8];
#pragma unroll
    for (int l = 0; l < 8; ++l)
        cc[l] = addrn(addrn(addrn(a[0][l], a[1][l]), a[2][l]), a[3][l]);
    float u0 = addrn(cc[0], cc[4]), u1 = addrn(cc[1], cc[5]);
    float u2 = addrn(cc[2], cc[6]), u3 = addrn(cc[3], cc[7]);
    return addrn(addrn(u0, u2), addrn(u1, u3));
}

// ------- pack: fp32 [R][256] -> fragment-blocked fp16 ----------------------
__global__ __launch_bounds__(256)
void vq_pack(const float* __restrict__ src, u16* __restrict__ dh,
             unsigned int* __restrict__ cnt) {
    if (cnt && blockIdx.x == 0 && threadIdx.x == 0) *cnt = 0;
    __shared__ __align__(16) float lx[16 * 260];
    const int t = threadIdx.x;
    const size_t base = (size_t)blockIdx.x * 16 * 256;
#pragma unroll
    for (int qq = 0; qq < 4; ++qq) {
        int i4 = qq * 256 + t;
        int row = i4 >> 6, col = (i4 & 63) * 4;
        *(float4*)(lx + row * 260 + col) = *(const float4*)(src + base + (size_t)i4 * 4);
    }
    __syncthreads();
#pragma unroll
    for (int i = 0; i < 2; ++i) {
        int s = t + 256 * i;
        int kb = s >> 6, lane = s & 63;
        int r = lane & 15, kg = lane >> 4;
        int k0 = kb * 32 + kg * 8;
        u16 vh[8];
#pragma unroll
        for (int j = 0; j < 8; ++j) {
            float v = lx[r * 260 + k0 + j];
            vh[j] = __half_as_ushort(__float2half(v));   // RNE
        }
        size_t off = (((size_t)blockIdx.x * 8 + kb) * 64 + lane) * 8;
        *(ulonglong2*)(dh + off) = *(ulonglong2*)vh;
    }
}

// ------- np/XLA-exact sum of squares (emb only) ----------------------------
__global__ __launch_bounds__(256)
void vq_sumsq_llvm(const float* __restrict__ src, float* __restrict__ out) {
    __shared__ float lx[64 * 257];
    const int t = threadIdx.x;
    const size_t base = (size_t)blockIdx.x * 64 * 256;
#pragma unroll
    for (int qq = 0; qq < 16; ++qq) {
        int idx4 = qq * 256 + t;
        int row = idx4 >> 6, col4 = idx4 & 63;
        *(float4*)(lx + row * 257 + col4 * 4) = *(const float4*)(src + base + (size_t)idx4 * 4);
    }
    __syncthreads();
    if (t < 64) out[blockIdx.x * 64 + t] = sumsq_vf8ic4(lx + t * 257);
}

// ------- MFMA fp16 single-pass GEMM, A persistent in LDS -------------------
__global__ __launch_bounds__(256, 2)
void vq_gemm(const u16* __restrict__ Ah, const u16* __restrict__ Eh,
             const float* __restrict__ esq, float* __restrict__ tw) {
    extern __shared__ u16 lds[];          // 80 KB
    u16* ldsA = lds;
    u16* ldsB = lds + 64 * 512;
    const int t = threadIdx.x;
    const int wave = t >> 6, lane = t & 63;
    const int wm = wave >> 1, wn = wave & 1;
    const int q = lane >> 4, c = lane & 15;
    const int m0 = blockIdx.x * 128;
    const int mrb8 = blockIdx.x * 64;

#pragma unroll
    for (int u = 0; u < 16; ++u) {
        int f = wave * 16 + u;
        const u16* srcp = Ah + ((size_t)(mrb8 + f) * 64 + lane) * 8;
        __builtin_amdgcn_global_load_lds((const unsigned int*)srcp,
                                         (unsigned int*)(ldsA + f * 512), 16, 0, 0);
    }
#pragma unroll
    for (int u = 0; u < 2; ++u) {
        int nf = wave * 2 + u;
        const u16* srcp = Eh + (((size_t)nf * 8 + 0) * 64 + lane) * 8;
        __builtin_amdgcn_global_load_lds((const unsigned int*)srcp,
                                         (unsigned int*)(ldsB + nf * 512), 16, 0, 0);
    }
    __syncthreads();

    float b1[16], s2v[16], bi[16];
#pragma unroll
    for (int r = 0; r < 16; ++r) { b1[r] = INFINITY; s2v[r] = INFINITY; bi[r] = 0.f; }

    f32x4 acc[4][4];
#pragma unroll
    for (int mi = 0; mi < 4; ++mi)
#pragma unroll
        for (int ni = 0; ni < 4; ++ni) acc[mi][ni] = 0.f;

    for (int step = 0; step < 64; ++step) {
        const int nqi = step >> 3, ks = step & 7, p = step & 1;
        if (step < 63) {
            const int ns = step + 1, nq2 = ns >> 3, ks2 = ns & 7, p2 = ns & 1;
#pragma unroll
            for (int u = 0; u < 2; ++u) {
                int nf = wave * 2 + u;
                const u16* srcp = Eh + (((size_t)(nq2 * 8 + nf) * 8 + ks2) * 64 + lane) * 8;
                __builtin_amdgcn_global_load_lds((const unsigned int*)srcp,
                                                 (unsigned int*)(ldsB + (p2 * 8 + nf) * 512), 16, 0, 0);
            }
        }
        hfrag af[4], bfv[4];
#pragma unroll
        for (int mi = 0; mi < 4; ++mi)
            af[mi] = *(const hfrag*)(ldsA + ((wm * 4 + mi) * 8 + ks) * 512 + lane * 8);
#pragma unroll
        for (int ni = 0; ni < 4; ++ni)
            bfv[ni] = *(const hfrag*)(ldsB + (p * 8 + wn * 4 + ni) * 512 + lane * 8);
#pragma unroll
        for (int mi = 0; mi < 4; ++mi)
#pragma unroll
            for (int ni = 0; ni < 4; ++ni)
                acc[mi][ni] = __builtin_amdgcn_mfma_f32_16x16x32_f16(af[mi], bfv[ni], acc[mi][ni], 0, 0, 0);

        if (ks == 7) {
#pragma unroll
            for (int ni = 0; ni < 4; ++ni) {
                const int code = nqi * 128 + wn * 64 + ni * 16 + c;
                const float e2 = esq[code];
                const float ci = (float)code;
#pragma unroll
                for (int mi = 0; mi < 4; ++mi)
#pragma unroll
                    for (int j = 0; j < 4; ++j) {
                        const int r = mi * 4 + j;
                        float sc = fmaf(-2.f, acc[mi][ni][j], e2);
                        bool lt = sc < b1[r];
                        s2v[r] = fminf(s2v[r], lt ? b1[r] : sc);
                        if (lt) { b1[r] = sc; bi[r] = ci; }
                    }
            }
#pragma unroll
            for (int mi = 0; mi < 4; ++mi)
#pragma unroll
                for (int ni = 0; ni < 4; ++ni) acc[mi][ni] = 0.f;
        }
        __syncthreads();
    }

#pragma unroll
    for (int r = 0; r < 16; ++r) {
#pragma unroll
        for (int mm = 1; mm < 16; mm <<= 1) {
            float ob = __shfl_xor(b1[r], mm, 64);
            float os = __shfl_xor(s2v[r], mm, 64);
            float oi = __shfl_xor(bi[r], mm, 64);
            if (ob < b1[r]) { s2v[r] = fminf(b1[r], os); b1[r] = ob; bi[r] = oi; }
            else            { s2v[r] = fminf(s2v[r], ob); }
        }
    }
    if (c == 0) {
#pragma unroll
        for (int mi = 0; mi < 4; ++mi)
#pragma unroll
            for (int j = 0; j < 4; ++j) {
                int row = m0 + wm * 64 + mi * 16 + q * 4 + j;
                size_t o = (size_t)row * 8 + wn * 4;
                int r = mi * 4 + j;
                tw[o + 0] = b1[r];
                tw[o + 1] = s2v[r];
                tw[o + 2] = bi[r];
            }
    }
}

// ------- merge wn partials; flag near-ties ---------------------------------
__global__ void vq_reduce2(const float* __restrict__ tw, float* __restrict__ idxf,
                           unsigned int* __restrict__ cnt, int* __restrict__ list) {
    int row = blockIdx.x * 256 + threadIdx.x;
    float b0 = tw[(size_t)row * 8 + 0], s0 = tw[(size_t)row * 8 + 1], i0 = tw[(size_t)row * 8 + 2];
    float b1 = tw[(size_t)row * 8 + 4], s1 = tw[(size_t)row * 8 + 5], i1 = tw[(size_t)row * 8 + 6];
    float b, s2, bidx;
    if (b0 <= b1) { b = b0; bidx = i0; s2 = fminf(s0, b1); }
    else          { b = b1; bidx = i1; s2 = fminf(s1, b0); }
    idxf[row] = bidx;
    if (s2 - b < MARGIN) {
        unsigned int pos = atomicAdd(cnt, 1u);
        list[pos] = row;
    }
}

// ------- exact refine pass 1: (8 rows) x (128-code chunk) partial argmin ----
__global__ __launch_bounds__(256)
void vq_refine1(const float* __restrict__ x, const float* __restrict__ emb,
                const float* __restrict__ esq, const int* __restrict__ list,
                const unsigned int* __restrict__ cnt, float2* __restrict__ part) {
    __shared__ __align__(16) float xs[8][260];
    __shared__ float xsq_s[8];
    const int t = threadIdx.x;
    const int chunk = blockIdx.y;
    const unsigned int n = *cnt;
    for (unsigned int g = blockIdx.x; g * 8u < n; g += gridDim.x) {
        const unsigned int r0 = g * 8u;
        const int nr = (int)min(8u, n - r0);
        __syncthreads();
#pragma unroll
        for (int u = 0; u < 2; ++u) {
            int s = u * 256 + t;
            int rr = s >> 6, l4 = s & 63;
            if (rr < nr) {
                int row = list[r0 + rr];
                *(float4*)(&xs[rr][l4 * 4]) = *(const float4*)(x + (size_t)row * 256 + l4 * 4);
            }
        }
        __syncthreads();
        if (t < nr) xsq_s[t] = sumsq_vf8ic4(&xs[t][0]);
        __syncthreads();
        const int r = t >> 5, l32 = t & 31;
        if (r < nr) {
            const float xq = xsq_s[r];
            const float* e0 = emb + (size_t)(chunk * 128 + l32) * 256;
            float d0 = 0.f, d1 = 0.f, d2 = 0.f, d3 = 0.f;
#pragma unroll 4
            for (int k = 0; k < 256; ++k) {      // ascending-k single chain per code
                float xv = xs[r][k];
                d0 = fmaf(xv, e0[k], d0);
                d1 = fmaf(xv, e0[k + 32 * 256], d1);
                d2 = fmaf(xv, e0[k + 64 * 256], d2);
                d3 = fmaf(xv, e0[k + 96 * 256], d3);
            }
            float best = INFINITY; int bi = 0x7fffffff;
            float dv[4] = { d0, d1, d2, d3 };
#pragma unroll
            for (int p = 0; p < 4; ++p) {
                int code = chunk * 128 + l32 + 32 * p;
                float s = addrn(fmaf(-2.f, dv[p], xq), esq[code]);
                if (s < best || (s == best && code < bi)) { best = s; bi = code; }
            }
#pragma unroll
            for (int mm = 1; mm < 32; mm <<= 1) {   // merge the 32 code-lanes
                float ob = __shfl_xor(best, mm, 64);
                int oi = __shfl_xor(bi, mm, 64);
                if (ob < best || (ob == best && oi < bi)) { best = ob; bi = oi; }
            }
            if (l32 == 0) part[(size_t)(r0 + r) * 8 + chunk] = make_float2(best, (float)bi);
        }
    }
}

// ------- exact refine pass 2: merge 8 chunk partials -----------------------
__global__ void vq_refine2(const float2* __restrict__ part, const int* __restrict__ list,
                           const unsigned int* __restrict__ cnt, float* __restrict__ idxf) {
    unsigned int u = blockIdx.x * 256u + threadIdx.x;
    unsigned int n = *cnt;
    if (u < n) {
        float best = INFINITY; int bi = 0x7fffffff;
#pragma unroll
        for (int y = 0; y < 8; ++y) {
            float2 pv = part[(size_t)u * 8 + y];
            int oi = (int)pv.y;
            if (pv.x < best || (pv.x == best && oi < bi)) { best = pv.x; bi = oi; }
        }
        idxf[list[u]] = (float)bi;
    }
}

// ------- gather ------------------------------------------------------------
__global__ void vq_gather(const float* __restrict__ emb, const float* __restrict__ idx_f,
                          float* __restrict__ qout) {
    int row = blockIdx.x * 4 + (threadIdx.x >> 6);
    int l = threadIdx.x & 63;
    int idx = (int)idx_f[row];
    float4 v = *(const float4*)(emb + (size_t)idx * KD + l * 4);
    *(float4*)(qout + (size_t)row * KD + l * 4) = v;
}

extern "C" void kernel_launch(void* const* d_in, const int* in_sizes, int n_in,
                              void* d_out, int out_size, void* d_ws, size_t ws_size,
                              hipStream_t stream) {
    const float* x   = (const float*)d_in[0];
    const float* emb = (const float*)d_in[1];
    float* out  = (float*)d_out;
    float* idxf = out + IOFF;

    u16* Ah = (u16*)out;                                   // [0, 32MB)
    float2* part = (float2*)((char*)d_out + (32u << 20));  // [32MB, 36MB)

    char* ws = (char*)d_ws;
    u16* Eh    = (u16*)(ws);
    float* esq = (float*)(ws + (512 << 10));
    float* tw  = (float*)(ws + (1 << 20));
    unsigned int* cnt = (unsigned int*)(ws + ((size_t)3 << 20) + (512 << 10));
    int* list = (int*)(ws + ((size_t)3 << 20) + (512 << 10) + 256);

    vq_pack<<<dim3(MROWS / 16), dim3(256), 0, stream>>>(x, Ah, cnt);
    vq_pack<<<dim3(NCODES / 16), dim3(256), 0, stream>>>(emb, Eh, nullptr);
    vq_sumsq_llvm<<<dim3(NCODES / 64), dim3(256), 0, stream>>>(emb, esq);
    vq_gemm<<<dim3(MROWS / 128), dim3(256), 81920, stream>>>(Ah, Eh, esq, tw);
    vq_reduce2<<<dim3(MROWS / 256), dim3(256), 0, stream>>>(tw, idxf, cnt, list);
    vq_refine1<<<dim3(512, 8), dim3(256), 0, stream>>>(x, emb, esq, list, cnt, part);
    vq_refine2<<<dim3(256), dim3(256), 0, stream>>>(part, list, cnt, idxf);
    vq_gather<<<dim3(MROWS / 4), dim3(256), 0, stream>>>(emb, idxf, out);
}

// Round 12
// 167.005 us; speedup vs baseline: 1.9637x; 1.9637x over previous
//
#include <hip/hip_runtime.h>
#include <hip/hip_fp16.h>
#include <math.h>

#define MROWS   65536
#define NCODES  1024
#define KD      256
#define MARGIN  0.25f
#define RPG     16          // flagged rows per refine group

typedef unsigned short u16;
typedef __attribute__((ext_vector_type(8))) _Float16 hfrag;  // 8 fp16 = 4 VGPR
typedef __attribute__((ext_vector_type(4))) float f32x4;

// d_out bytes: [0,32M) Ah fp16 scratch | [32M,34M) refine partials | everything in
//   [0,64M) overwritten by vq_gather last | idx floats at [64M,+256K).
// d_ws: [0,512K) Eh | [512K,+4K) esq | [1M,+2M) tw | [3.5M] cnt | +256B list
#define IOFF ((size_t)MROWS * KD)

// ---- asm-rounded fp32 add (contraction/reassociation-proof) ---------------
__device__ __forceinline__ float addrn(float a, float b) {
    float d; asm("v_add_f32 %0, %1, %2" : "=v"(d) : "v"(a), "v"(b)); return d;
}

// ---- exact VF8-IC4 sum of squares of a 256-row (R8-verified bits) ---------
__device__ __forceinline__ float sumsq_vf8ic4(const float* __restrict__ xr) {
    float a[4][8];
#pragma unroll
    for (int i = 0; i < 4; ++i)
#pragma unroll
        for (int l = 0; l < 8; ++l) a[i][l] = 0.f;
#pragma unroll
    for (int m = 0; m < 8; ++m)
#pragma unroll
        for (int i = 0; i < 4; ++i)
#pragma unroll
            for (int l = 0; l < 8; ++l) {
                float v = xr[m * 32 + i * 8 + l];
                a[i][l] = fmaf(v, v, a[i][l]);
            }
    float cc[8];
#pragma unroll
    for (int l = 0; l < 8; ++l)
        cc[l] = addrn(addrn(addrn(a[0][l], a[1][l]), a[2][l]), a[3][l]);
    float u0 = addrn(cc[0], cc[4]), u1 = addrn(cc[1], cc[5]);
    float u2 = addrn(cc[2], cc[6]), u3 = addrn(cc[3], cc[7]);
    return addrn(addrn(u0, u2), addrn(u1, u3));
}

// ------- pack: fp32 [R][256] -> fragment-blocked fp16 ----------------------
__global__ __launch_bounds__(256)
void vq_pack(const float* __restrict__ src, u16* __restrict__ dh,
             unsigned int* __restrict__ cnt) {
    if (cnt && blockIdx.x == 0 && threadIdx.x == 0) *cnt = 0;
    __shared__ __align__(16) float lx[16 * 260];
    const int t = threadIdx.x;
    const size_t base = (size_t)blockIdx.x * 16 * 256;
#pragma unroll
    for (int qq = 0; qq < 4; ++qq) {
        int i4 = qq * 256 + t;
        int row = i4 >> 6, col = (i4 & 63) * 4;
        *(float4*)(lx + row * 260 + col) = *(const float4*)(src + base + (size_t)i4 * 4);
    }
    __syncthreads();
#pragma unroll
    for (int i = 0; i < 2; ++i) {
        int s = t + 256 * i;
        int kb = s >> 6, lane = s & 63;
        int r = lane & 15, kg = lane >> 4;
        int k0 = kb * 32 + kg * 8;
        u16 vh[8];
#pragma unroll
        for (int j = 0; j < 8; ++j) {
            float v = lx[r * 260 + k0 + j];
            vh[j] = __half_as_ushort(__float2half(v));   // RNE
        }
        size_t off = (((size_t)blockIdx.x * 8 + kb) * 64 + lane) * 8;
        *(ulonglong2*)(dh + off) = *(ulonglong2*)vh;
    }
}

// ------- np/XLA-exact sum of squares (emb only) ----------------------------
__global__ __launch_bounds__(256)
void vq_sumsq_llvm(const float* __restrict__ src, float* __restrict__ out) {
    __shared__ float lx[64 * 257];
    const int t = threadIdx.x;
    const size_t base = (size_t)blockIdx.x * 64 * 256;
#pragma unroll
    for (int qq = 0; qq < 16; ++qq) {
        int idx4 = qq * 256 + t;
        int row = idx4 >> 6, col4 = idx4 & 63;
        *(float4*)(lx + row * 257 + col4 * 4) = *(const float4*)(src + base + (size_t)idx4 * 4);
    }
    __syncthreads();
    if (t < 64) out[blockIdx.x * 64 + t] = sumsq_vf8ic4(lx + t * 257);
}

// ------- MFMA fp16 single-pass GEMM, A persistent in LDS -------------------
__global__ __launch_bounds__(256, 2)
void vq_gemm(const u16* __restrict__ Ah, const u16* __restrict__ Eh,
             const float* __restrict__ esq, float* __restrict__ tw) {
    extern __shared__ u16 lds[];          // 80 KB
    u16* ldsA = lds;
    u16* ldsB = lds + 64 * 512;
    const int t = threadIdx.x;
    const int wave = t >> 6, lane = t & 63;
    const int wm = wave >> 1, wn = wave & 1;
    const int q = lane >> 4, c = lane & 15;
    const int m0 = blockIdx.x * 128;
    const int mrb8 = blockIdx.x * 64;

#pragma unroll
    for (int u = 0; u < 16; ++u) {
        int f = wave * 16 + u;
        const u16* srcp = Ah + ((size_t)(mrb8 + f) * 64 + lane) * 8;
        __builtin_amdgcn_global_load_lds((const unsigned int*)srcp,
                                         (unsigned int*)(ldsA + f * 512), 16, 0, 0);
    }
#pragma unroll
    for (int u = 0; u < 2; ++u) {
        int nf = wave * 2 + u;
        const u16* srcp = Eh + (((size_t)nf * 8 + 0) * 64 + lane) * 8;
        __builtin_amdgcn_global_load_lds((const unsigned int*)srcp,
                                         (unsigned int*)(ldsB + nf * 512), 16, 0, 0);
    }
    __syncthreads();

    float b1[16], s2v[16], bi[16];
#pragma unroll
    for (int r = 0; r < 16; ++r) { b1[r] = INFINITY; s2v[r] = INFINITY; bi[r] = 0.f; }

    f32x4 acc[4][4];
#pragma unroll
    for (int mi = 0; mi < 4; ++mi)
#pragma unroll
        for (int ni = 0; ni < 4; ++ni) acc[mi][ni] = 0.f;

    for (int step = 0; step < 64; ++step) {
        const int nqi = step >> 3, ks = step & 7, p = step & 1;
        if (step < 63) {
            const int ns = step + 1, nq2 = ns >> 3, ks2 = ns & 7, p2 = ns & 1;
#pragma unroll
            for (int u = 0; u < 2; ++u) {
                int nf = wave * 2 + u;
                const u16* srcp = Eh + (((size_t)(nq2 * 8 + nf) * 8 + ks2) * 64 + lane) * 8;
                __builtin_amdgcn_global_load_lds((const unsigned int*)srcp,
                                                 (unsigned int*)(ldsB + (p2 * 8 + nf) * 512), 16, 0, 0);
            }
        }
        hfrag af[4], bfv[4];
#pragma unroll
        for (int mi = 0; mi < 4; ++mi)
            af[mi] = *(const hfrag*)(ldsA + ((wm * 4 + mi) * 8 + ks) * 512 + lane * 8);
#pragma unroll
        for (int ni = 0; ni < 4; ++ni)
            bfv[ni] = *(const hfrag*)(ldsB + (p * 8 + wn * 4 + ni) * 512 + lane * 8);
#pragma unroll
        for (int mi = 0; mi < 4; ++mi)
#pragma unroll
            for (int ni = 0; ni < 4; ++ni)
                acc[mi][ni] = __builtin_amdgcn_mfma_f32_16x16x32_f16(af[mi], bfv[ni], acc[mi][ni], 0, 0, 0);

        if (ks == 7) {
#pragma unroll
            for (int ni = 0; ni < 4; ++ni) {
                const int code = nqi * 128 + wn * 64 + ni * 16 + c;
                const float e2 = esq[code];
                const float ci = (float)code;
#pragma unroll
                for (int mi = 0; mi < 4; ++mi)
#pragma unroll
                    for (int j = 0; j < 4; ++j) {
                        const int r = mi * 4 + j;
                        float sc = fmaf(-2.f, acc[mi][ni][j], e2);
                        bool lt = sc < b1[r];
                        s2v[r] = fminf(s2v[r], lt ? b1[r] : sc);
                        if (lt) { b1[r] = sc; bi[r] = ci; }
                    }
            }
#pragma unroll
            for (int mi = 0; mi < 4; ++mi)
#pragma unroll
                for (int ni = 0; ni < 4; ++ni) acc[mi][ni] = 0.f;
        }
        __syncthreads();
    }

#pragma unroll
    for (int r = 0; r < 16; ++r) {
#pragma unroll
        for (int mm = 1; mm < 16; mm <<= 1) {
            float ob = __shfl_xor(b1[r], mm, 64);
            float os = __shfl_xor(s2v[r], mm, 64);
            float oi = __shfl_xor(bi[r], mm, 64);
            if (ob < b1[r]) { s2v[r] = fminf(b1[r], os); b1[r] = ob; bi[r] = oi; }
            else            { s2v[r] = fminf(s2v[r], ob); }
        }
    }
    if (c == 0) {
#pragma unroll
        for (int mi = 0; mi < 4; ++mi)
#pragma unroll
            for (int j = 0; j < 4; ++j) {
                int row = m0 + wm * 64 + mi * 16 + q * 4 + j;
                size_t o = (size_t)row * 8 + wn * 4;
                int r = mi * 4 + j;
                tw[o + 0] = b1[r];
                tw[o + 1] = s2v[r];
                tw[o + 2] = bi[r];
            }
    }
}

// ------- merge wn partials; flag near-ties ---------------------------------
__global__ void vq_reduce2(const float* __restrict__ tw, float* __restrict__ idxf,
                           unsigned int* __restrict__ cnt, int* __restrict__ list) {
    int row = blockIdx.x * 256 + threadIdx.x;
    float b0 = tw[(size_t)row * 8 + 0], s0 = tw[(size_t)row * 8 + 1], i0 = tw[(size_t)row * 8 + 2];
    float b1 = tw[(size_t)row * 8 + 4], s1 = tw[(size_t)row * 8 + 5], i1 = tw[(size_t)row * 8 + 6];
    float b, s2, bidx;
    if (b0 <= b1) { b = b0; bidx = i0; s2 = fminf(s0, b1); }
    else          { b = b1; bidx = i1; s2 = fminf(s1, b0); }
    idxf[row] = bidx;
    if (s2 - b < MARGIN) {
        unsigned int pos = atomicAdd(cnt, 1u);
        list[pos] = row;
    }
}

// ------- exact refine pass 1: 16 rows x 256-code chunk, LDS-staged ---------
__global__ __launch_bounds__(256)
void vq_refine1(const float* __restrict__ x, const float* __restrict__ emb,
                const float* __restrict__ esq, const int* __restrict__ list,
                const unsigned int* __restrict__ cnt, float2* __restrict__ part) {
    __shared__ __align__(16) float xs[RPG][260];
    __shared__ __align__(16) float es[256][36];   // k-tile of 32, stride 36 (conflict-free)
    __shared__ float xsq_s[RPG];
    __shared__ float lb[RPG][4];
    __shared__ int   li[RPG][4];
    const int t = threadIdx.x;
    const int wave = t >> 6, lane = t & 63;
    const int chunk = blockIdx.y;
    const int c = chunk * 256 + t;                // this thread's code
    const unsigned int n = *cnt;
    for (unsigned int g = blockIdx.x; g * RPG < n; g += gridDim.x) {
        const unsigned int r0 = g * RPG;
        const int nr = (int)min((unsigned)RPG, n - r0);
        __syncthreads();
#pragma unroll
        for (int u = 0; u < RPG / 4; ++u) {       // RPG rows x 64 float4
            int s = u * 256 + t;
            int rr = s >> 6, l4 = s & 63;
            if (rr < nr) {
                int row = list[r0 + rr];
                *(float4*)(&xs[rr][l4 * 4]) = *(const float4*)(x + (size_t)row * 256 + l4 * 4);
            }
        }
        __syncthreads();
        if (t < nr) xsq_s[t] = sumsq_vf8ic4(&xs[t][0]);
        __syncthreads();

        float d[RPG];
#pragma unroll
        for (int r = 0; r < RPG; ++r) d[r] = 0.f;

        for (int kt = 0; kt < 8; ++kt) {
            // stage emb k-tile: 256 codes x 32 k, coalesced
#pragma unroll
            for (int u = 0; u < 8; ++u) {
                int i = u * 256 + t;
                int cc = i >> 3, k4 = i & 7;
                float4 v = *(const float4*)(emb + (size_t)(chunk * 256 + cc) * 256 + kt * 32 + k4 * 4);
                *(float4*)(&es[cc][k4 * 4]) = v;
            }
            __syncthreads();
#pragma unroll
            for (int qq = 0; qq < 8; ++qq) {
                float4 e4 = *(const float4*)(&es[t][qq * 4]);
#pragma unroll
                for (int r = 0; r < RPG; ++r) {
                    float4 xf = *(const float4*)(&xs[r][kt * 32 + qq * 4]);
                    d[r] = fmaf(xf.x, e4.x, d[r]);
                    d[r] = fmaf(xf.y, e4.y, d[r]);
                    d[r] = fmaf(xf.z, e4.z, d[r]);
                    d[r] = fmaf(xf.w, e4.w, d[r]);
                }
            }
            __syncthreads();
        }
        const float e2 = esq[c];
#pragma unroll
        for (int r = 0; r < RPG; ++r) {
            float sv = addrn(fmaf(-2.f, d[r], xsq_s[r]), e2);
            int bc = c;
#pragma unroll
            for (int mm = 1; mm < 64; mm <<= 1) {
                float ob = __shfl_xor(sv, mm, 64);
                int oi = __shfl_xor(bc, mm, 64);
                if (ob < sv || (ob == sv && oi < bc)) { sv = ob; bc = oi; }
            }
            if (lane == 0) { lb[r][wave] = sv; li[r][wave] = bc; }
        }
        __syncthreads();
        if (t < nr) {
            float best = lb[t][0]; int bix = li[t][0];
#pragma unroll
            for (int w = 1; w < 4; ++w) {
                float ob = lb[t][w]; int oi = li[t][w];
                if (ob < best || (ob == best && oi < bix)) { best = ob; bix = oi; }
            }
            part[(size_t)(r0 + t) * 4 + chunk] = make_float2(best, (float)bix);
        }
    }
}

// ------- exact refine pass 2: merge 4 chunk partials -----------------------
__global__ void vq_refine2(const float2* __restrict__ part, const int* __restrict__ list,
                           const unsigned int* __restrict__ cnt, float* __restrict__ idxf) {
    unsigned int u = blockIdx.x * 256u + threadIdx.x;
    unsigned int n = *cnt;
    if (u < n) {
        float best = INFINITY; int bi = 0x7fffffff;
#pragma unroll
        for (int y = 0; y < 4; ++y) {
            float2 pv = part[(size_t)u * 4 + y];
            int oi = (int)pv.y;
            if (pv.x < best || (pv.x == best && oi < bi)) { best = pv.x; bi = oi; }
        }
        idxf[list[u]] = (float)bi;
    }
}

// ------- gather ------------------------------------------------------------
__global__ void vq_gather(const float* __restrict__ emb, const float* __restrict__ idx_f,
                          float* __restrict__ qout) {
    int row = blockIdx.x * 4 + (threadIdx.x >> 6);
    int l = threadIdx.x & 63;
    int idx = (int)idx_f[row];
    float4 v = *(const float4*)(emb + (size_t)idx * KD + l * 4);
    *(float4*)(qout + (size_t)row * KD + l * 4) = v;
}

extern "C" void kernel_launch(void* const* d_in, const int* in_sizes, int n_in,
                              void* d_out, int out_size, void* d_ws, size_t ws_size,
                              hipStream_t stream) {
    const float* x   = (const float*)d_in[0];
    const float* emb = (const float*)d_in[1];
    float* out  = (float*)d_out;
    float* idxf = out + IOFF;

    u16* Ah = (u16*)out;                                   // [0, 32MB)
    float2* part = (float2*)((char*)d_out + (32u << 20));  // [32MB, 34MB)

    char* ws = (char*)d_ws;
    u16* Eh    = (u16*)(ws);
    float* esq = (float*)(ws + (512 << 10));
    float* tw  = (float*)(ws + (1 << 20));
    unsigned int* cnt = (unsigned int*)(ws + ((size_t)3 << 20) + (512 << 10));
    int* list = (int*)(ws + ((size_t)3 << 20) + (512 << 10) + 256);

    vq_pack<<<dim3(MROWS / 16), dim3(256), 0, stream>>>(x, Ah, cnt);
    vq_pack<<<dim3(NCODES / 16), dim3(256), 0, stream>>>(emb, Eh, nullptr);
    vq_sumsq_llvm<<<dim3(NCODES / 64), dim3(256), 0, stream>>>(emb, esq);
    vq_gemm<<<dim3(MROWS / 128), dim3(256), 81920, stream>>>(Ah, Eh, esq, tw);
    vq_reduce2<<<dim3(MROWS / 256), dim3(256), 0, stream>>>(tw, idxf, cnt, list);
    vq_refine1<<<dim3(512, 4), dim3(256), 0, stream>>>(x, emb, esq, list, cnt, part);
    vq_refine2<<<dim3(256), dim3(256), 0, stream>>>(part, list, cnt, idxf);
    vq_gather<<<dim3(MROWS / 4), dim3(256), 0, stream>>>(emb, idxf, out);
}

// Round 13
// 140.594 us; speedup vs baseline: 2.3325x; 1.1879x over previous
//
#include <hip/hip_runtime.h>
#include <hip/hip_fp16.h>
#include <math.h>

#define MROWS   65536
#define NCODES  1024
#define KD      256
#define MARGIN  0.25f

typedef unsigned short u16;
typedef __attribute__((ext_vector_type(8))) _Float16 hfrag;  // 8 fp16 = 4 VGPR
typedef __attribute__((ext_vector_type(4))) float f32x4;

// d_out bytes: [0,32M) Ah fp16 scratch | [32M,33M) embT | all of [0,64M) overwritten
//   by vq_gather last | idx floats at [64M,+256K).
// d_ws: [0,512K) Eh | [512K,+4K) esq | [1M,+2M) tw | [3.5M] cnt | +256B list
#define IOFF ((size_t)MROWS * KD)

// ---- asm-rounded fp32 add (contraction/reassociation-proof) ---------------
__device__ __forceinline__ float addrn(float a, float b) {
    float d; asm("v_add_f32 %0, %1, %2" : "=v"(d) : "v"(a), "v"(b)); return d;
}

// ---- exact VF8-IC4 sum of squares of a 256-row (R8-verified bits) ---------
__device__ __forceinline__ float sumsq_vf8ic4(const float* __restrict__ xr) {
    float a[4][8];
#pragma unroll
    for (int i = 0; i < 4; ++i)
#pragma unroll
        for (int l = 0; l < 8; ++l) a[i][l] = 0.f;
#pragma unroll
    for (int m = 0; m < 8; ++m)
#pragma unroll
        for (int i = 0; i < 4; ++i)
#pragma unroll
            for (int l = 0; l < 8; ++l) {
                float v = xr[m * 32 + i * 8 + l];
                a[i][l] = fmaf(v, v, a[i][l]);
            }
    float cc[8];
#pragma unroll
    for (int l = 0; l < 8; ++l)
        cc[l] = addrn(addrn(addrn(a[0][l], a[1][l]), a[2][l]), a[3][l]);
    float u0 = addrn(cc[0], cc[4]), u1 = addrn(cc[1], cc[5]);
    float u2 = addrn(cc[2], cc[6]), u3 = addrn(cc[3], cc[7]);
    return addrn(addrn(u0, u2), addrn(u1, u3));
}

// ------- pack: fp32 [R][256] -> fragment-blocked fp16 ----------------------
__global__ __launch_bounds__(256)
void vq_pack(const float* __restrict__ src, u16* __restrict__ dh,
             unsigned int* __restrict__ cnt) {
    if (cnt && blockIdx.x == 0 && threadIdx.x == 0) *cnt = 0;
    __shared__ __align__(16) float lx[16 * 260];
    const int t = threadIdx.x;
    const size_t base = (size_t)blockIdx.x * 16 * 256;
#pragma unroll
    for (int qq = 0; qq < 4; ++qq) {
        int i4 = qq * 256 + t;
        int row = i4 >> 6, col = (i4 & 63) * 4;
        *(float4*)(lx + row * 260 + col) = *(const float4*)(src + base + (size_t)i4 * 4);
    }
    __syncthreads();
#pragma unroll
    for (int i = 0; i < 2; ++i) {
        int s = t + 256 * i;
        int kb = s >> 6, lane = s & 63;
        int r = lane & 15, kg = lane >> 4;
        int k0 = kb * 32 + kg * 8;
        u16 vh[8];
#pragma unroll
        for (int j = 0; j < 8; ++j) {
            float v = lx[r * 260 + k0 + j];
            vh[j] = __half_as_ushort(__float2half(v));   // RNE
        }
        size_t off = (((size_t)blockIdx.x * 8 + kb) * 64 + lane) * 8;
        *(ulonglong2*)(dh + off) = *(ulonglong2*)vh;
    }
}

// ------- np/XLA-exact sum of squares (emb only) ----------------------------
__global__ __launch_bounds__(256)
void vq_sumsq_llvm(const float* __restrict__ src, float* __restrict__ out) {
    __shared__ float lx[64 * 257];
    const int t = threadIdx.x;
    const size_t base = (size_t)blockIdx.x * 64 * 256;
#pragma unroll
    for (int qq = 0; qq < 16; ++qq) {
        int idx4 = qq * 256 + t;
        int row = idx4 >> 6, col4 = idx4 & 63;
        *(float4*)(lx + row * 257 + col4 * 4) = *(const float4*)(src + base + (size_t)idx4 * 4);
    }
    __syncthreads();
    if (t < 64) out[blockIdx.x * 64 + t] = sumsq_vf8ic4(lx + t * 257);
}

// ------- transpose emb [1024][256] -> embT [256][1024] ---------------------
__global__ __launch_bounds__(256)
void vq_transpose(const float* __restrict__ emb, float* __restrict__ embT) {
    __shared__ float ld[64][65];
    const int t = threadIdx.x;
    const int c0 = blockIdx.x * 64, k0 = blockIdx.y * 64;
#pragma unroll
    for (int u = 0; u < 16; ++u) {
        int i = u * 256 + t;
        int r = i >> 6, col = i & 63;
        ld[r][col] = emb[(size_t)(c0 + r) * 256 + k0 + col];
    }
    __syncthreads();
#pragma unroll
    for (int u = 0; u < 16; ++u) {
        int i = u * 256 + t;
        int r = i >> 6, col = i & 63;
        embT[(size_t)(k0 + r) * 1024 + c0 + col] = ld[col][r];
    }
}

// ------- MFMA fp16 single-pass GEMM, A persistent in LDS -------------------
__global__ __launch_bounds__(256, 2)
void vq_gemm(const u16* __restrict__ Ah, const u16* __restrict__ Eh,
             const float* __restrict__ esq, float* __restrict__ tw) {
    extern __shared__ u16 lds[];          // 80 KB
    u16* ldsA = lds;
    u16* ldsB = lds + 64 * 512;
    const int t = threadIdx.x;
    const int wave = t >> 6, lane = t & 63;
    const int wm = wave >> 1, wn = wave & 1;
    const int q = lane >> 4, c = lane & 15;
    const int m0 = blockIdx.x * 128;
    const int mrb8 = blockIdx.x * 64;

#pragma unroll
    for (int u = 0; u < 16; ++u) {
        int f = wave * 16 + u;
        const u16* srcp = Ah + ((size_t)(mrb8 + f) * 64 + lane) * 8;
        __builtin_amdgcn_global_load_lds((const unsigned int*)srcp,
                                         (unsigned int*)(ldsA + f * 512), 16, 0, 0);
    }
#pragma unroll
    for (int u = 0; u < 2; ++u) {
        int nf = wave * 2 + u;
        const u16* srcp = Eh + (((size_t)nf * 8 + 0) * 64 + lane) * 8;
        __builtin_amdgcn_global_load_lds((const unsigned int*)srcp,
                                         (unsigned int*)(ldsB + nf * 512), 16, 0, 0);
    }
    __syncthreads();

    float b1[16], s2v[16], bi[16];
#pragma unroll
    for (int r = 0; r < 16; ++r) { b1[r] = INFINITY; s2v[r] = INFINITY; bi[r] = 0.f; }

    f32x4 acc[4][4];
#pragma unroll
    for (int mi = 0; mi < 4; ++mi)
#pragma unroll
        for (int ni = 0; ni < 4; ++ni) acc[mi][ni] = 0.f;

    for (int step = 0; step < 64; ++step) {
        const int nqi = step >> 3, ks = step & 7, p = step & 1;
        if (step < 63) {
            const int ns = step + 1, nq2 = ns >> 3, ks2 = ns & 7, p2 = ns & 1;
#pragma unroll
            for (int u = 0; u < 2; ++u) {
                int nf = wave * 2 + u;
                const u16* srcp = Eh + (((size_t)(nq2 * 8 + nf) * 8 + ks2) * 64 + lane) * 8;
                __builtin_amdgcn_global_load_lds((const unsigned int*)srcp,
                                                 (unsigned int*)(ldsB + (p2 * 8 + nf) * 512), 16, 0, 0);
            }
        }
        hfrag af[4], bfv[4];
#pragma unroll
        for (int mi = 0; mi < 4; ++mi)
            af[mi] = *(const hfrag*)(ldsA + ((wm * 4 + mi) * 8 + ks) * 512 + lane * 8);
#pragma unroll
        for (int ni = 0; ni < 4; ++ni)
            bfv[ni] = *(const hfrag*)(ldsB + (p * 8 + wn * 4 + ni) * 512 + lane * 8);
#pragma unroll
        for (int mi = 0; mi < 4; ++mi)
#pragma unroll
            for (int ni = 0; ni < 4; ++ni)
                acc[mi][ni] = __builtin_amdgcn_mfma_f32_16x16x32_f16(af[mi], bfv[ni], acc[mi][ni], 0, 0, 0);

        if (ks == 7) {
#pragma unroll
            for (int ni = 0; ni < 4; ++ni) {
                const int code = nqi * 128 + wn * 64 + ni * 16 + c;
                const float e2 = esq[code];
                const float ci = (float)code;
#pragma unroll
                for (int mi = 0; mi < 4; ++mi)
#pragma unroll
                    for (int j = 0; j < 4; ++j) {
                        const int r = mi * 4 + j;
                        float sc = fmaf(-2.f, acc[mi][ni][j], e2);
                        bool lt = sc < b1[r];
                        s2v[r] = fminf(s2v[r], lt ? b1[r] : sc);
                        if (lt) { b1[r] = sc; bi[r] = ci; }
                    }
            }
#pragma unroll
            for (int mi = 0; mi < 4; ++mi)
#pragma unroll
                for (int ni = 0; ni < 4; ++ni) acc[mi][ni] = 0.f;
        }
        __syncthreads();
    }

#pragma unroll
    for (int r = 0; r < 16; ++r) {
#pragma unroll
        for (int mm = 1; mm < 16; mm <<= 1) {
            float ob = __shfl_xor(b1[r], mm, 64);
            float os = __shfl_xor(s2v[r], mm, 64);
            float oi = __shfl_xor(bi[r], mm, 64);
            if (ob < b1[r]) { s2v[r] = fminf(b1[r], os); b1[r] = ob; bi[r] = oi; }
            else            { s2v[r] = fminf(s2v[r], ob); }
        }
    }
    if (c == 0) {
#pragma unroll
        for (int mi = 0; mi < 4; ++mi)
#pragma unroll
            for (int j = 0; j < 4; ++j) {
                int row = m0 + wm * 64 + mi * 16 + q * 4 + j;
                size_t o = (size_t)row * 8 + wn * 4;
                int r = mi * 4 + j;
                tw[o + 0] = b1[r];
                tw[o + 1] = s2v[r];
                tw[o + 2] = bi[r];
            }
    }
}

// ------- merge wn partials; flag near-ties ---------------------------------
__global__ void vq_reduce2(const float* __restrict__ tw, float* __restrict__ idxf,
                           unsigned int* __restrict__ cnt, int* __restrict__ list) {
    int row = blockIdx.x * 256 + threadIdx.x;
    float b0 = tw[(size_t)row * 8 + 0], s0 = tw[(size_t)row * 8 + 1], i0 = tw[(size_t)row * 8 + 2];
    float b1 = tw[(size_t)row * 8 + 4], s1 = tw[(size_t)row * 8 + 5], i1 = tw[(size_t)row * 8 + 6];
    float b, s2, bidx;
    if (b0 <= b1) { b = b0; bidx = i0; s2 = fminf(s0, b1); }
    else          { b = b1; bidx = i1; s2 = fminf(s1, b0); }
    idxf[row] = bidx;
    if (s2 - b < MARGIN) {
        unsigned int pos = atomicAdd(cnt, 1u);
        list[pos] = row;
    }
}

// ------- exact refine: 8 rows/group, 4 codes/thread, embT coalesced --------
__global__ __launch_bounds__(256)
void vq_refine1(const float* __restrict__ x, const float* __restrict__ embT,
                const float* __restrict__ esq, const int* __restrict__ list,
                const unsigned int* __restrict__ cnt, float* __restrict__ idxf) {
    __shared__ __align__(16) float xs[8][260];
    __shared__ float xsq_s[8];
    __shared__ float lb[8][4];
    __shared__ int   li[8][4];
    const int t = threadIdx.x;
    const int wave = t >> 6, lane = t & 63;
    const unsigned int n = *cnt;
    float e2q[4];
#pragma unroll
    for (int qq = 0; qq < 4; ++qq) e2q[qq] = esq[qq * 256 + t];

    for (unsigned int g = blockIdx.x; g * 8u < n; g += gridDim.x) {
        const unsigned int r0 = g * 8u;
        const int nr = (int)min(8u, n - r0);
        __syncthreads();
#pragma unroll
        for (int u = 0; u < 2; ++u) {
            int s = u * 256 + t;
            int rr = s >> 6, l4 = s & 63;
            if (rr < nr) {
                int row = list[r0 + rr];
                *(float4*)(&xs[rr][l4 * 4]) = *(const float4*)(x + (size_t)row * 256 + l4 * 4);
            }
        }
        __syncthreads();
        if (t < nr) xsq_s[t] = sumsq_vf8ic4(&xs[t][0]);
        __syncthreads();

        float d[8][4];
#pragma unroll
        for (int r = 0; r < 8; ++r)
#pragma unroll
            for (int qq = 0; qq < 4; ++qq) d[r][qq] = 0.f;

        for (int kq = 0; kq < 64; ++kq) {
            float ev[4][4];
#pragma unroll
            for (int j = 0; j < 4; ++j)
#pragma unroll
                for (int qq = 0; qq < 4; ++qq)
                    ev[qq][j] = embT[(size_t)(kq * 4 + j) * 1024 + qq * 256 + t];
            float4 xf[8];
#pragma unroll
            for (int r = 0; r < 8; ++r) xf[r] = *(const float4*)(&xs[r][kq * 4]);
#pragma unroll
            for (int r = 0; r < 8; ++r)
#pragma unroll
                for (int qq = 0; qq < 4; ++qq) {
                    d[r][qq] = fmaf(xf[r].x, ev[qq][0], d[r][qq]);
                    d[r][qq] = fmaf(xf[r].y, ev[qq][1], d[r][qq]);
                    d[r][qq] = fmaf(xf[r].z, ev[qq][2], d[r][qq]);
                    d[r][qq] = fmaf(xf[r].w, ev[qq][3], d[r][qq]);
                }
        }
#pragma unroll
        for (int r = 0; r < 8; ++r) {
            float sv = INFINITY; int bc = 0x7fffffff;
#pragma unroll
            for (int qq = 0; qq < 4; ++qq) {   // ascending code order -> strict < keeps min idx
                float s = addrn(fmaf(-2.f, d[r][qq], xsq_s[r]), e2q[qq]);
                if (s < sv) { sv = s; bc = qq * 256 + t; }
            }
#pragma unroll
            for (int mm = 1; mm < 64; mm <<= 1) {
                float ob = __shfl_xor(sv, mm, 64);
                int oi = __shfl_xor(bc, mm, 64);
                if (ob < sv || (ob == sv && oi < bc)) { sv = ob; bc = oi; }
            }
            if (lane == 0) { lb[r][wave] = sv; li[r][wave] = bc; }
        }
        __syncthreads();
        if (t < nr) {
            float best = lb[t][0]; int bix = li[t][0];
#pragma unroll
            for (int w = 1; w < 4; ++w) {
                float ob = lb[t][w]; int oi = li[t][w];
                if (ob < best || (ob == best && oi < bix)) { best = ob; bix = oi; }
            }
            idxf[list[r0 + t]] = (float)bix;
        }
    }
}

// ------- gather ------------------------------------------------------------
__global__ void vq_gather(const float* __restrict__ emb, const float* __restrict__ idx_f,
                          float* __restrict__ qout) {
    int row = blockIdx.x * 4 + (threadIdx.x >> 6);
    int l = threadIdx.x & 63;
    int idx = (int)idx_f[row];
    float4 v = *(const float4*)(emb + (size_t)idx * KD + l * 4);
    *(float4*)(qout + (size_t)row * KD + l * 4) = v;
}

extern "C" void kernel_launch(void* const* d_in, const int* in_sizes, int n_in,
                              void* d_out, int out_size, void* d_ws, size_t ws_size,
                              hipStream_t stream) {
    const float* x   = (const float*)d_in[0];
    const float* emb = (const float*)d_in[1];
    float* out  = (float*)d_out;
    float* idxf = out + IOFF;

    u16* Ah = (u16*)out;                                 // [0, 32MB)
    float* embT = (float*)((char*)d_out + (32u << 20));  // [32MB, 33MB)

    char* ws = (char*)d_ws;
    u16* Eh    = (u16*)(ws);
    float* esq = (float*)(ws + (512 << 10));
    float* tw  = (float*)(ws + (1 << 20));
    unsigned int* cnt = (unsigned int*)(ws + ((size_t)3 << 20) + (512 << 10));
    int* list = (int*)(ws + ((size_t)3 << 20) + (512 << 10) + 256);

    vq_pack<<<dim3(MROWS / 16), dim3(256), 0, stream>>>(x, Ah, cnt);
    vq_pack<<<dim3(NCODES / 16), dim3(256), 0, stream>>>(emb, Eh, nullptr);
    vq_sumsq_llvm<<<dim3(NCODES / 64), dim3(256), 0, stream>>>(emb, esq);
    vq_transpose<<<dim3(16, 4), dim3(256), 0, stream>>>(emb, embT);
    vq_gemm<<<dim3(MROWS / 128), dim3(256), 81920, stream>>>(Ah, Eh, esq, tw);
    vq_reduce2<<<dim3(MROWS / 256), dim3(256), 0, stream>>>(tw, idxf, cnt, list);
    vq_refine1<<<dim3(512), dim3(256), 0, stream>>>(x, embT, esq, list, cnt, idxf);
    vq_gather<<<dim3(MROWS / 4), dim3(256), 0, stream>>>(emb, idxf, out);
}

// Round 14
// 138.842 us; speedup vs baseline: 2.3620x; 1.0126x over previous
//
#include <hip/hip_runtime.h>
#include <hip/hip_fp16.h>
#include <math.h>

#define MROWS   65536
#define NCODES  1024
#define KD      256
#define MARGIN  0.25f

typedef unsigned short u16;
typedef __attribute__((ext_vector_type(8))) _Float16 hfrag;  // 8 fp16 = 4 VGPR
typedef __attribute__((ext_vector_type(4))) float f32x4;

// d_out bytes: [0,32M) Ah fp16 scratch | [32M,33M) embT | all of [0,64M) overwritten
//   by vq_gather last | idx floats at [64M,+256K).
// d_ws: [0,512K) Eh | [512K,+4K) esq | [1M,+2M) tw | [3.5M] cnt | +256B list
#define IOFF ((size_t)MROWS * KD)

// ---- asm-rounded fp32 add (contraction/reassociation-proof) ---------------
__device__ __forceinline__ float addrn(float a, float b) {
    float d; asm("v_add_f32 %0, %1, %2" : "=v"(d) : "v"(a), "v"(b)); return d;
}

// ---- exact VF8-IC4 sum of squares of a 256-row (R8-verified bits) ---------
__device__ __forceinline__ float sumsq_vf8ic4(const float* __restrict__ xr) {
    float a[4][8];
#pragma unroll
    for (int i = 0; i < 4; ++i)
#pragma unroll
        for (int l = 0; l < 8; ++l) a[i][l] = 0.f;
#pragma unroll
    for (int m = 0; m < 8; ++m)
#pragma unroll
        for (int i = 0; i < 4; ++i)
#pragma unroll
            for (int l = 0; l < 8; ++l) {
                float v = xr[m * 32 + i * 8 + l];
                a[i][l] = fmaf(v, v, a[i][l]);
            }
    float cc[8];
#pragma unroll
    for (int l = 0; l < 8; ++l)
        cc[l] = addrn(addrn(addrn(a[0][l], a[1][l]), a[2][l]), a[3][l]);
    float u0 = addrn(cc[0], cc[4]), u1 = addrn(cc[1], cc[5]);
    float u2 = addrn(cc[2], cc[6]), u3 = addrn(cc[3], cc[7]);
    return addrn(addrn(u0, u2), addrn(u1, u3));
}

// ------- pack: fp32 [R][256] -> fragment-blocked fp16 ----------------------
__global__ __launch_bounds__(256)
void vq_pack(const float* __restrict__ src, u16* __restrict__ dh,
             unsigned int* __restrict__ cnt) {
    if (cnt && blockIdx.x == 0 && threadIdx.x == 0) *cnt = 0;
    __shared__ __align__(16) float lx[16 * 260];
    const int t = threadIdx.x;
    const size_t base = (size_t)blockIdx.x * 16 * 256;
#pragma unroll
    for (int qq = 0; qq < 4; ++qq) {
        int i4 = qq * 256 + t;
        int row = i4 >> 6, col = (i4 & 63) * 4;
        *(float4*)(lx + row * 260 + col) = *(const float4*)(src + base + (size_t)i4 * 4);
    }
    __syncthreads();
#pragma unroll
    for (int i = 0; i < 2; ++i) {
        int s = t + 256 * i;
        int kb = s >> 6, lane = s & 63;
        int r = lane & 15, kg = lane >> 4;
        int k0 = kb * 32 + kg * 8;
        u16 vh[8];
#pragma unroll
        for (int j = 0; j < 8; ++j) {
            float v = lx[r * 260 + k0 + j];
            vh[j] = __half_as_ushort(__float2half(v));   // RNE
        }
        size_t off = (((size_t)blockIdx.x * 8 + kb) * 64 + lane) * 8;
        *(ulonglong2*)(dh + off) = *(ulonglong2*)vh;
    }
}

// ------- np/XLA-exact sum of squares (emb only) ----------------------------
__global__ __launch_bounds__(256)
void vq_sumsq_llvm(const float* __restrict__ src, float* __restrict__ out) {
    __shared__ float lx[64 * 257];
    const int t = threadIdx.x;
    const size_t base = (size_t)blockIdx.x * 64 * 256;
#pragma unroll
    for (int qq = 0; qq < 16; ++qq) {
        int idx4 = qq * 256 + t;
        int row = idx4 >> 6, col4 = idx4 & 63;
        *(float4*)(lx + row * 257 + col4 * 4) = *(const float4*)(src + base + (size_t)idx4 * 4);
    }
    __syncthreads();
    if (t < 64) out[blockIdx.x * 64 + t] = sumsq_vf8ic4(lx + t * 257);
}

// ------- transpose emb [1024][256] -> embT [256][1024] ---------------------
__global__ __launch_bounds__(256)
void vq_transpose(const float* __restrict__ emb, float* __restrict__ embT) {
    __shared__ float ld[64][65];
    const int t = threadIdx.x;
    const int c0 = blockIdx.x * 64, k0 = blockIdx.y * 64;
#pragma unroll
    for (int u = 0; u < 16; ++u) {
        int i = u * 256 + t;
        int r = i >> 6, col = i & 63;
        ld[r][col] = emb[(size_t)(c0 + r) * 256 + k0 + col];
    }
    __syncthreads();
#pragma unroll
    for (int u = 0; u < 16; ++u) {
        int i = u * 256 + t;
        int r = i >> 6, col = i & 63;
        embT[(size_t)(k0 + r) * 1024 + c0 + col] = ld[col][r];
    }
}

// ------- MFMA fp16 GEMM: A persistent in LDS, B register-pipelined ---------
__global__ __launch_bounds__(256, 2)
void vq_gemm(const u16* __restrict__ Ah, const u16* __restrict__ Eh,
             const float* __restrict__ esq, float* __restrict__ tw) {
    extern __shared__ u16 ldsA[];         // 64 KB: 64 A-frags x 512 u16
    const int t = threadIdx.x;
    const int wave = t >> 6, lane = t & 63;
    const int wm = wave >> 1, wn = wave & 1;
    const int q = lane >> 4, c = lane & 15;
    const int m0 = blockIdx.x * 128;
    const int mrb8 = blockIdx.x * 64;

    // stage entire A tile (64 frags, 64 KB) — single barrier, read-only after
#pragma unroll
    for (int u = 0; u < 16; ++u) {
        int f = wave * 16 + u;
        const u16* srcp = Ah + ((size_t)(mrb8 + f) * 64 + lane) * 8;
        __builtin_amdgcn_global_load_lds((const unsigned int*)srcp,
                                         (unsigned int*)(ldsA + f * 512), 16, 0, 0);
    }
    __syncthreads();

    // B fragment loader: step s -> frag f = (s>>3)*64 + (wn*4+ni)*8 + (s&7)
    auto LOADB = [&](int s, hfrag* dst) {
        const int f0 = ((s >> 3) * 64) + (wn * 4) * 8 + (s & 7);
#pragma unroll
        for (int ni = 0; ni < 4; ++ni)
            dst[ni] = *(const hfrag*)(Eh + (size_t)(f0 + ni * 8) * 512 + lane * 8);
    };
    auto LDA = [&](int s, hfrag* dst) {
        const int ks = s & 7;
#pragma unroll
        for (int mi = 0; mi < 4; ++mi)
            dst[mi] = *(const hfrag*)(ldsA + ((wm * 4 + mi) * 8 + ks) * 512 + lane * 8);
    };

    float b1[16], s2v[16], bi[16];
#pragma unroll
    for (int r = 0; r < 16; ++r) { b1[r] = INFINITY; s2v[r] = INFINITY; bi[r] = 0.f; }

    f32x4 acc[4][4];
#pragma unroll
    for (int mi = 0; mi < 4; ++mi)
#pragma unroll
        for (int ni = 0; ni < 4; ++ni) acc[mi][ni] = 0.f;

    hfrag bA[4], bB[4];
    LOADB(0, bA);
    LOADB(1, bB);

    for (int sp = 0; sp < 32; ++sp) {
        const int s0 = sp * 2, s1 = sp * 2 + 1;
        // ---- even step: compute with bA ----
        {
            hfrag nx[4];
            LOADB(s0 + 2 < 64 ? s0 + 2 : 0, nx);   // clamped dummy on last iter
            hfrag af[4];
            LDA(s0, af);
#pragma unroll
            for (int mi = 0; mi < 4; ++mi)
#pragma unroll
                for (int ni = 0; ni < 4; ++ni)
                    acc[mi][ni] = __builtin_amdgcn_mfma_f32_16x16x32_f16(af[mi], bA[ni], acc[mi][ni], 0, 0, 0);
#pragma unroll
            for (int ni = 0; ni < 4; ++ni) bA[ni] = nx[ni];
        }
        // ---- odd step: compute with bB ----
        {
            hfrag nx[4];
            LOADB(s1 + 2 < 64 ? s1 + 2 : 0, nx);
            hfrag af[4];
            LDA(s1, af);
#pragma unroll
            for (int mi = 0; mi < 4; ++mi)
#pragma unroll
                for (int ni = 0; ni < 4; ++ni)
                    acc[mi][ni] = __builtin_amdgcn_mfma_f32_16x16x32_f16(af[mi], bB[ni], acc[mi][ni], 0, 0, 0);
#pragma unroll
            for (int ni = 0; ni < 4; ++ni) bB[ni] = nx[ni];
        }
        // ---- epilogue after each full K pass (s1 = 7 mod 8) ----
        if ((s1 & 7) == 7) {
            const int nqi = s1 >> 3;
#pragma unroll
            for (int ni = 0; ni < 4; ++ni) {
                const int code = nqi * 128 + wn * 64 + ni * 16 + c;
                const float e2 = esq[code];
                const float ci = (float)code;
#pragma unroll
                for (int mi = 0; mi < 4; ++mi)
#pragma unroll
                    for (int j = 0; j < 4; ++j) {
                        const int r = mi * 4 + j;
                        float sc = fmaf(-2.f, acc[mi][ni][j], e2);
                        bool lt = sc < b1[r];
                        s2v[r] = fminf(s2v[r], lt ? b1[r] : sc);
                        if (lt) { b1[r] = sc; bi[r] = ci; }
                    }
            }
#pragma unroll
            for (int mi = 0; mi < 4; ++mi)
#pragma unroll
                for (int ni = 0; ni < 4; ++ni) acc[mi][ni] = 0.f;
        }
    }

#pragma unroll
    for (int r = 0; r < 16; ++r) {
#pragma unroll
        for (int mm = 1; mm < 16; mm <<= 1) {
            float ob = __shfl_xor(b1[r], mm, 64);
            float os = __shfl_xor(s2v[r], mm, 64);
            float oi = __shfl_xor(bi[r], mm, 64);
            if (ob < b1[r]) { s2v[r] = fminf(b1[r], os); b1[r] = ob; bi[r] = oi; }
            else            { s2v[r] = fminf(s2v[r], ob); }
        }
    }
    if (c == 0) {
#pragma unroll
        for (int mi = 0; mi < 4; ++mi)
#pragma unroll
            for (int j = 0; j < 4; ++j) {
                int row = m0 + wm * 64 + mi * 16 + q * 4 + j;
                size_t o = (size_t)row * 8 + wn * 4;
                int r = mi * 4 + j;
                tw[o + 0] = b1[r];
                tw[o + 1] = s2v[r];
                tw[o + 2] = bi[r];
            }
    }
}

// ------- merge wn partials; flag near-ties ---------------------------------
__global__ void vq_reduce2(const float* __restrict__ tw, float* __restrict__ idxf,
                           unsigned int* __restrict__ cnt, int* __restrict__ list) {
    int row = blockIdx.x * 256 + threadIdx.x;
    float b0 = tw[(size_t)row * 8 + 0], s0 = tw[(size_t)row * 8 + 1], i0 = tw[(size_t)row * 8 + 2];
    float b1 = tw[(size_t)row * 8 + 4], s1 = tw[(size_t)row * 8 + 5], i1 = tw[(size_t)row * 8 + 6];
    float b, s2, bidx;
    if (b0 <= b1) { b = b0; bidx = i0; s2 = fminf(s0, b1); }
    else          { b = b1; bidx = i1; s2 = fminf(s1, b0); }
    idxf[row] = bidx;
    if (s2 - b < MARGIN) {
        unsigned int pos = atomicAdd(cnt, 1u);
        list[pos] = row;
    }
}

// ------- exact refine: 8 rows/group, 4 codes/thread, embT coalesced --------
__global__ __launch_bounds__(256)
void vq_refine1(const float* __restrict__ x, const float* __restrict__ embT,
                const float* __restrict__ esq, const int* __restrict__ list,
                const unsigned int* __restrict__ cnt, float* __restrict__ idxf) {
    __shared__ __align__(16) float xs[8][260];
    __shared__ float xsq_s[8];
    __shared__ float lb[8][4];
    __shared__ int   li[8][4];
    const int t = threadIdx.x;
    const int wave = t >> 6, lane = t & 63;
    const unsigned int n = *cnt;
    float e2q[4];
#pragma unroll
    for (int qq = 0; qq < 4; ++qq) e2q[qq] = esq[qq * 256 + t];

    for (unsigned int g = blockIdx.x; g * 8u < n; g += gridDim.x) {
        const unsigned int r0 = g * 8u;
        const int nr = (int)min(8u, n - r0);
        __syncthreads();
#pragma unroll
        for (int u = 0; u < 2; ++u) {
            int s = u * 256 + t;
            int rr = s >> 6, l4 = s & 63;
            if (rr < nr) {
                int row = list[r0 + rr];
                *(float4*)(&xs[rr][l4 * 4]) = *(const float4*)(x + (size_t)row * 256 + l4 * 4);
            }
        }
        __syncthreads();
        if (t < nr) xsq_s[t] = sumsq_vf8ic4(&xs[t][0]);
        __syncthreads();

        float d[8][4];
#pragma unroll
        for (int r = 0; r < 8; ++r)
#pragma unroll
            for (int qq = 0; qq < 4; ++qq) d[r][qq] = 0.f;

        for (int kq = 0; kq < 64; ++kq) {
            float ev[4][4];
#pragma unroll
            for (int j = 0; j < 4; ++j)
#pragma unroll
                for (int qq = 0; qq < 4; ++qq)
                    ev[qq][j] = embT[(size_t)(kq * 4 + j) * 1024 + qq * 256 + t];
            float4 xf[8];
#pragma unroll
            for (int r = 0; r < 8; ++r) xf[r] = *(const float4*)(&xs[r][kq * 4]);
#pragma unroll
            for (int r = 0; r < 8; ++r)
#pragma unroll
                for (int qq = 0; qq < 4; ++qq) {
                    d[r][qq] = fmaf(xf[r].x, ev[qq][0], d[r][qq]);
                    d[r][qq] = fmaf(xf[r].y, ev[qq][1], d[r][qq]);
                    d[r][qq] = fmaf(xf[r].z, ev[qq][2], d[r][qq]);
                    d[r][qq] = fmaf(xf[r].w, ev[qq][3], d[r][qq]);
                }
        }
#pragma unroll
        for (int r = 0; r < 8; ++r) {
            float sv = INFINITY; int bc = 0x7fffffff;
#pragma unroll
            for (int qq = 0; qq < 4; ++qq) {   // ascending code order -> strict < keeps min idx
                float s = addrn(fmaf(-2.f, d[r][qq], xsq_s[r]), e2q[qq]);
                if (s < sv) { sv = s; bc = qq * 256 + t; }
            }
#pragma unroll
            for (int mm = 1; mm < 64; mm <<= 1) {
                float ob = __shfl_xor(sv, mm, 64);
                int oi = __shfl_xor(bc, mm, 64);
                if (ob < sv || (ob == sv && oi < bc)) { sv = ob; bc = oi; }
            }
            if (lane == 0) { lb[r][wave] = sv; li[r][wave] = bc; }
        }
        __syncthreads();
        if (t < nr) {
            float best = lb[t][0]; int bix = li[t][0];
#pragma unroll
            for (int w = 1; w < 4; ++w) {
                float ob = lb[t][w]; int oi = li[t][w];
                if (ob < best || (ob == best && oi < bix)) { best = ob; bix = oi; }
            }
            idxf[list[r0 + t]] = (float)bix;
        }
    }
}

// ------- gather ------------------------------------------------------------
__global__ void vq_gather(const float* __restrict__ emb, const float* __restrict__ idx_f,
                          float* __restrict__ qout) {
    int row = blockIdx.x * 4 + (threadIdx.x >> 6);
    int l = threadIdx.x & 63;
    int idx = (int)idx_f[row];
    float4 v = *(const float4*)(emb + (size_t)idx * KD + l * 4);
    *(float4*)(qout + (size_t)row * KD + l * 4) = v;
}

extern "C" void kernel_launch(void* const* d_in, const int* in_sizes, int n_in,
                              void* d_out, int out_size, void* d_ws, size_t ws_size,
                              hipStream_t stream) {
    const float* x   = (const float*)d_in[0];
    const float* emb = (const float*)d_in[1];
    float* out  = (float*)d_out;
    float* idxf = out + IOFF;

    u16* Ah = (u16*)out;                                 // [0, 32MB)
    float* embT = (float*)((char*)d_out + (32u << 20));  // [32MB, 33MB)

    char* ws = (char*)d_ws;
    u16* Eh    = (u16*)(ws);
    float* esq = (float*)(ws + (512 << 10));
    float* tw  = (float*)(ws + (1 << 20));
    unsigned int* cnt = (unsigned int*)(ws + ((size_t)3 << 20) + (512 << 10));
    int* list = (int*)(ws + ((size_t)3 << 20) + (512 << 10) + 256);

    vq_pack<<<dim3(MROWS / 16), dim3(256), 0, stream>>>(x, Ah, cnt);
    vq_pack<<<dim3(NCODES / 16), dim3(256), 0, stream>>>(emb, Eh, nullptr);
    vq_sumsq_llvm<<<dim3(NCODES / 64), dim3(256), 0, stream>>>(emb, esq);
    vq_transpose<<<dim3(16, 4), dim3(256), 0, stream>>>(emb, embT);
    vq_gemm<<<dim3(MROWS / 128), dim3(256), 65536, stream>>>(Ah, Eh, esq, tw);
    vq_reduce2<<<dim3(MROWS / 256), dim3(256), 0, stream>>>(tw, idxf, cnt, list);
    vq_refine1<<<dim3(512), dim3(256), 0, stream>>>(x, embT, esq, list, cnt, idxf);
    vq_gather<<<dim3(MROWS / 4), dim3(256), 0, stream>>>(emb, idxf, out);
}